// Round 8
// baseline (112.646 us; speedup 1.0000x reference)
//
#include <hip/hip_runtime.h>

// Symmetrizer for MAX_L=3.
//   out[:,:,0,:]   = in[:,:,0,:]
//   out[:,:,1+s,:] = sum_{k: slot[k]==s} pref[k] * in[:,:,k+1,:]^2
// Tables bench-verified (round 3): every pair is a square of ang k=1..19;
//   l=1 pref {1,1,1}; l=2 {1,2,2,1,2,1}; l=3 {1,3,3,3,6,3,1,3,3,1}.
//
// ROUND 7: barrier-free per-wave double-buffered pipeline.
//  - Key: with flat staging order, wave w stages exactly the rows it
//    computes -> NO __syncthreads anywhere (no vmcnt(0) drain, no
//    phase-locking of the 2 resident blocks that plagued round 6).
//  - global_load_lds width=16, linear LDS (stride 304 dw, no pad; read-side
//    2-way bank aliasing is free per m136).
//  - Double buffer: issue 19 gll + 1 ang0 load for tile t+1, then counted
//    s_waitcnt vmcnt(20) = "all but my 20 prefetch ops done" (vmcnt retires
//    in order, m135), compute tile t, store, swap. vmcnt never hits 0 in
//    the loop -> 20 KB always in flight per wave, 4 waves/CU = 80 KB/CU
//    >> Little's-law ~25 KB -> HBM demand continuous by construction.
//  - Persistent grid: 1024 one-wave blocks (4/CU, LDS-bound), 25000 tiles.

typedef float f32x4 __attribute__((ext_vector_type(4)));

constexpr int ROWS_PT      = 16;                  // rows per wave-tile
constexpr int IN_ROW_F4    = 80;                  // 20 angs * 4 f4
constexpr int OUT_ROW_F4   = 16;                  // 4 angs * 4 f4
constexpr int STAGE_F4     = 76;                  // angs 1..19
constexpr int TILE_F4      = ROWS_PT * STAGE_F4;  // 1216
constexpr int GLL_PER_TILE = TILE_F4 / 64;        // 19
constexpr int BUF_DW       = TILE_F4 * 4;         // 4864 dwords / buffer
constexpr int GRID_BLOCKS  = 1024;                // 4 per CU, persistent

__device__ __forceinline__ void gload_lds16(const float* g, float* l) {
    __builtin_amdgcn_global_load_lds(
        (const __attribute__((address_space(1))) void*)g,
        (__attribute__((address_space(3))) void*)l,
        16, 0, 0);
}

__global__ __launch_bounds__(64) void symmetrizer_kernel(
    const float* __restrict__ in,   // flat f32, rows of 320
    f32x4*       __restrict__ out,  // [rows][4][4]
    int n_tiles)
{
    extern __shared__ float lds[];  // 2 * 4864 dwords = 38912 B
    const int t  = threadIdx.x;     // 0..63 (one wave)
    const int r  = t >> 2;          // local row 0..15
    const int c4 = t & 3;           // channel quad

    int tile = blockIdx.x;
    int cur  = 0;

    // ---- prologue: stage tile -> buf0, load its ang0 ----
    {
        const float* gb = in + (size_t)tile * ROWS_PT * IN_ROW_F4 * 4;
#pragma unroll
        for (int i = 0; i < GLL_PER_TILE; ++i) {
            unsigned f  = i * 64 + t;           // 0..1215
            unsigned rr = f / STAGE_F4;         // magic-mul
            unsigned jj = f - rr * STAGE_F4;
            gload_lds16(gb + (rr * IN_ROW_F4 + 4u + jj) * 4u,
                        &lds[i * 256]);         // wave-uniform base, HW adds lane*16
        }
    }
    f32x4 v0c = *(const f32x4*)(in +
        ((size_t)(tile * ROWS_PT + r) * IN_ROW_F4 + c4) * 4);

    while (true) {
        const int  next     = tile + GRID_BLOCKS;
        const bool has_next = next < n_tiles;
        f32x4 v0n;

        if (has_next) {
            // issue next tile's prefetch (19 gll + 1 ang0) -- no wait
            const float* gb = in + (size_t)next * ROWS_PT * IN_ROW_F4 * 4;
#pragma unroll
            for (int i = 0; i < GLL_PER_TILE; ++i) {
                unsigned f  = i * 64 + t;
                unsigned rr = f / STAGE_F4;
                unsigned jj = f - rr * STAGE_F4;
                gload_lds16(gb + (rr * IN_ROW_F4 + 4u + jj) * 4u,
                            &lds[(cur ^ 1) * BUF_DW + i * 256]);
            }
            v0n = *(const f32x4*)(in +
                ((size_t)(next * ROWS_PT + r) * IN_ROW_F4 + c4) * 4);
            // all but my 20 just-issued prefetch ops are done ->
            // current buffer's gll (issued last iteration) complete.
            asm volatile("s_waitcnt vmcnt(20)" ::: "memory");
        } else {
            asm volatile("s_waitcnt vmcnt(0)" ::: "memory");
        }
        __builtin_amdgcn_sched_barrier(0);

        // ---- compute current tile from LDS (2-way bank alias: free) ----
        const float* lb = &lds[cur * BUF_DW + r * (STAGE_F4 * 4) + c4 * 4];
        f32x4 d[19];
#pragma unroll
        for (int k = 0; k < 19; ++k)
            d[k] = *(const f32x4*)(lb + k * 16);   // ang k+1

        f32x4 s0 = d[0] * d[0] + d[1] * d[1] + d[2] * d[2];
        f32x4 s1 = d[3] * d[3] + 2.f * (d[4] * d[4]) + 2.f * (d[5] * d[5])
                 + d[6] * d[6] + 2.f * (d[7] * d[7]) + d[8] * d[8];
        f32x4 s2 = d[9] * d[9]   + 3.f * (d[10] * d[10]) + 3.f * (d[11] * d[11])
                 + 3.f * (d[12] * d[12]) + 6.f * (d[13] * d[13])
                 + 3.f * (d[14] * d[14]) + d[15] * d[15]
                 + 3.f * (d[16] * d[16]) + d[18] * d[18]
                 + 3.f * (d[17] * d[17]);

        f32x4* ob = out + (size_t)(tile * ROWS_PT + r) * OUT_ROW_F4 + c4;
        __builtin_nontemporal_store(v0c, ob + 0);
        __builtin_nontemporal_store(s0,  ob + 4);
        __builtin_nontemporal_store(s1,  ob + 8);
        __builtin_nontemporal_store(s2,  ob + 12);

        if (!has_next) break;
        v0c = v0n;
        tile = next;
        cur ^= 1;
    }
}

extern "C" void kernel_launch(void* const* d_in, const int* in_sizes, int n_in,
                              void* d_out, int out_size, void* d_ws, size_t ws_size,
                              hipStream_t stream) {
    const float* node_attr = (const float*)d_in[0];
    float*       out       = (float*)d_out;

    int rows    = in_sizes[0] / (20 * 16);   // 400000
    int n_tiles = rows / ROWS_PT;            // 25000 (exact)
    size_t lds_bytes = 2 * BUF_DW * sizeof(float);  // 38912

    symmetrizer_kernel<<<GRID_BLOCKS, 64, lds_bytes, stream>>>(
        node_attr, (f32x4*)out, n_tiles);
}

// Round 9
// 110.566 us; speedup vs baseline: 1.0188x; 1.0188x over previous
//
#include <hip/hip_runtime.h>

// Symmetrizer for MAX_L=3.
//   out[:,:,0,:]   = in[:,:,0,:]
//   out[:,:,1+s,:] = sum_{k: slot[k]==s} pref[k] * in[:,:,k+1,:]^2
// Tables bench-verified (round 3): every pair is a square of ang k=1..19;
//   l=1 pref {1,1,1}; l=2 {1,2,2,1,2,1}; l=3 {1,3,3,3,6,3,1,3,3,1}.
//
// FINAL (revert to round-6 structure, best measured: 110.8 us = 5.55 TB/s).
// Session ladder:
//   116.1  direct scattered 64B-segment reads (round 3)
//   153.1  + nontemporal loads  -> L2 is the read aggregator; REGRESSED
//   115.9  nt stores only       -> neutral
//   110.8  LDS-staged flat contiguous reads, barriered (round 6)  << BEST
//   112.6  barrier-free counted-vmcnt double-buffer  -> neutral
// Three independent structures converge at ~5.5 TB/s for this 5:1
// read:write one-touch mix (88% of the 6.29 TB/s 1:1-copy ceiling) ->
// platform roofline for this traffic mix.
//
// Structure: each 256-thread block stages angs 1..19 of 64 rows as a FLAT
// stream (consecutive lanes -> consecutive float4, ~1024 B per wave instr),
// then computes from LDS.
//   - LDS row stride 308 dwords: mod 32 = 20 -> uniform 8 lanes/bank for
//     ds_{read,write}_b128 (conflict-free minimum); mult of 4 -> 16B aligned.
//   - 64 rows x 1232 B = 78848 B dynamic LDS -> 2 blocks/CU.
//   - ang0 passthrough loaded direct; nt stores (write-once output).

typedef float f32x4 __attribute__((ext_vector_type(4)));

constexpr int ROWS_PB     = 64;          // rows per block
constexpr int IN_ROW_F4   = 80;          // 20 angs * 4 f4
constexpr int OUT_ROW_F4  = 16;          // 4 angs * 4 f4
constexpr int STAGE_F4    = 76;          // angs 1..19 per row
constexpr int LDS_STRIDE_DW = 308;       // padded row stride (dwords)
constexpr int LOADS_PT    = (ROWS_PB * STAGE_F4) / 256;  // 19

__global__ __launch_bounds__(256) void symmetrizer_kernel(
    const f32x4* __restrict__ in,   // [rows][20][4]
    f32x4*       __restrict__ out)  // [rows][4][4]
{
    extern __shared__ float lds[];  // 78848 B

    const int t = threadIdx.x;
    const size_t base_f4 = (size_t)blockIdx.x * ROWS_PB * IN_ROW_F4;

    // ---- Load phase: flat contiguous stream of angs 1..19, 64 rows ----
    f32x4 g[LOADS_PT];
    unsigned rr[LOADS_PT], ww[LOADS_PT];
#pragma unroll
    for (int i = 0; i < LOADS_PT; ++i) {
        unsigned f = (unsigned)(i * 256 + t);      // 0 .. 4863
        unsigned r = f / STAGE_F4;                 // compiler magic-mul
        unsigned w = f - r * STAGE_F4;             // 0 .. 75
        rr[i] = r; ww[i] = w;
        g[i] = in[base_f4 + r * IN_ROW_F4 + 4 + w];  // +4 f4 skips ang0
    }
#pragma unroll
    for (int i = 0; i < LOADS_PT; ++i) {
        *(f32x4*)&lds[rr[i] * LDS_STRIDE_DW + ww[i] * 4] = g[i];
    }

    // ---- per-thread compute identity ----
    const int r  = t >> 2;   // local row 0..63
    const int c4 = t & 3;    // channel quad

    // ang0 passthrough: issue before the barrier so it overlaps
    f32x4 v0 = in[base_f4 + (size_t)r * IN_ROW_F4 + c4];

    __syncthreads();

    // ---- Compute phase: conflict-free LDS reads ----
    const int rb = r * LDS_STRIDE_DW + c4 * 4;
    f32x4 d[19];
#pragma unroll
    for (int k = 0; k < 19; ++k) {
        d[k] = *(const f32x4*)&lds[rb + k * 16];   // ang k+1
    }

    // slot 0 (l=1): pref 1,1,1
    f32x4 s0 = d[0] * d[0] + d[1] * d[1] + d[2] * d[2];

    // slot 1 (l=2): pref 1,2,2,1,2,1
    f32x4 s1 = d[3] * d[3] + 2.f * (d[4] * d[4]) + 2.f * (d[5] * d[5])
             + d[6] * d[6] + 2.f * (d[7] * d[7]) + d[8] * d[8];

    // slot 2 (l=3): pref 1,3,3,3,6,3,1,3,3,1
    f32x4 s2 = d[9] * d[9]  + 3.f * (d[10] * d[10]) + 3.f * (d[11] * d[11])
             + 3.f * (d[12] * d[12]) + 6.f * (d[13] * d[13])
             + 3.f * (d[14] * d[14]) + d[15] * d[15]
             + 3.f * (d[16] * d[16]) + 3.f * (d[17] * d[17])
             + d[18] * d[18];

    f32x4* ob = out + ((size_t)blockIdx.x * ROWS_PB + r) * OUT_ROW_F4 + c4;
    __builtin_nontemporal_store(v0, ob + 0);
    __builtin_nontemporal_store(s0, ob + 4);
    __builtin_nontemporal_store(s1, ob + 8);
    __builtin_nontemporal_store(s2, ob + 12);
}

extern "C" void kernel_launch(void* const* d_in, const int* in_sizes, int n_in,
                              void* d_out, int out_size, void* d_ws, size_t ws_size,
                              hipStream_t stream) {
    const float* node_attr = (const float*)d_in[0];
    float*       out       = (float*)d_out;

    int rows   = in_sizes[0] / (20 * 16);       // 400000
    int blocks = rows / ROWS_PB;                // 6250 (exact)
    size_t lds_bytes = ROWS_PB * LDS_STRIDE_DW * sizeof(float);  // 78848

    symmetrizer_kernel<<<blocks, 256, lds_bytes, stream>>>(
        (const f32x4*)node_attr, (f32x4*)out);
}